// Round 12
// baseline (266.624 us; speedup 1.0000x reference)
//
#include <hip/hip_runtime.h>

#define Bsz 4096
#define Tlen 512
#define IND 18
#define HD 12
#define L2E 1.44269504088896340736f

typedef float v2 __attribute__((ext_vector_type(2)));
typedef float v4f __attribute__((ext_vector_type(4)));

__device__ __forceinline__ v2 pkfma(v2 a, v2 b, v2 c) {
  return __builtin_elementwise_fma(a, b, c);  // v_pk_fma_f32
}
__device__ __forceinline__ v2 vlo(v4f a) { return (v2){a.x, a.y}; }
__device__ __forceinline__ v2 vhi(v4f a) { return (v2){a.z, a.w}; }
// args pre-scaled: sigmoid arg by log2e, tanh arg by 2*log2e (folded into weights)
__device__ __forceinline__ float sigmoid_s(float x) {
  return __builtin_amdgcn_rcpf(1.f + __builtin_amdgcn_exp2f(-x));
}
__device__ __forceinline__ float tanh_s(float x) {
  return 1.f - 2.f * __builtin_amdgcn_rcpf(1.f + __builtin_amdgcn_exp2f(x));
}

// MERGED single-wave kernel: each 16-lane group owns one batch and runs the
// WHOLE network (layer0 + layer1 + FC) — zero barriers, zero inter-wave
// coupling. Per step, the independent blocks (hh1+FC on h2[t-1], proj of
// x[t+1]) statically cover both LDS broadcast round trips (h1, h2).
// Packed v_pk_fma_f32 dots, exp2-prescaled gate weights, 3-step-ahead x
// prefetch. 256 blocks x 4 waves = 1024 waves = 1 wave/SIMD (issue-bound by
// design; ~260 VGPR is free at 1 wave/SIMD).
extern "C" __global__ void __launch_bounds__(256, 1) gru2_merged(
    const float* __restrict__ x,
    const float* __restrict__ wih0, const float* __restrict__ whh0,
    const float* __restrict__ bih0, const float* __restrict__ bhh0,
    const float* __restrict__ wih1, const float* __restrict__ whh1,
    const float* __restrict__ bih1, const float* __restrict__ bhh1,
    const float* __restrict__ fcw, const float* __restrict__ fcb,
    float* __restrict__ out)
{
  const int tid    = threadIdx.x;
  const int lane15 = tid & 15;
  const int g      = tid >> 4;           // batch within block (0..15)
  const int b      = blockIdx.x * 16 + g;
  const int j      = (lane15 < HD) ? lane15 : (HD - 1);

  __shared__ float h1buf[16][16];        // wave-private broadcast slots
  __shared__ float h2buf[16][16];
  float* sp = &h1buf[g][0];
  float* sq = &h2buf[g][0];

  // ---- layer0 ih (k-pairs, scaled) ----
  v2 wr2[9], wz2[9], wn2[9];
#pragma unroll
  for (int i = 0; i < 9; ++i) {
    wr2[i] = (v2){ wih0[(0*HD+j)*IND + 2*i] * L2E,       wih0[(0*HD+j)*IND + 2*i+1] * L2E };
    wz2[i] = (v2){ wih0[(1*HD+j)*IND + 2*i] * L2E,       wih0[(1*HD+j)*IND + 2*i+1] * L2E };
    wn2[i] = (v2){ wih0[(2*HD+j)*IND + 2*i] * (2*L2E),   wih0[(2*HD+j)*IND + 2*i+1] * (2*L2E) };
  }
  // ---- layer0 hh / layer1 ih / layer1 hh / fc ----
  v2 ur2[6], uz2[6], un2[6], vr2[6], vz2[6], vn2[6], sr2[6], sz2[6], sn2[6], fw2[6];
#pragma unroll
  for (int i = 0; i < 6; ++i) {
    ur2[i] = (v2){ whh0[(0*HD+j)*HD + 2*i] * L2E,      whh0[(0*HD+j)*HD + 2*i+1] * L2E };
    uz2[i] = (v2){ whh0[(1*HD+j)*HD + 2*i] * L2E,      whh0[(1*HD+j)*HD + 2*i+1] * L2E };
    un2[i] = (v2){ whh0[(2*HD+j)*HD + 2*i] * (2*L2E),  whh0[(2*HD+j)*HD + 2*i+1] * (2*L2E) };
    vr2[i] = (v2){ wih1[(0*HD+j)*HD + 2*i] * L2E,      wih1[(0*HD+j)*HD + 2*i+1] * L2E };
    vz2[i] = (v2){ wih1[(1*HD+j)*HD + 2*i] * L2E,      wih1[(1*HD+j)*HD + 2*i+1] * L2E };
    vn2[i] = (v2){ wih1[(2*HD+j)*HD + 2*i] * (2*L2E),  wih1[(2*HD+j)*HD + 2*i+1] * (2*L2E) };
    sr2[i] = (v2){ whh1[(0*HD+j)*HD + 2*i] * L2E,      whh1[(0*HD+j)*HD + 2*i+1] * L2E };
    sz2[i] = (v2){ whh1[(1*HD+j)*HD + 2*i] * L2E,      whh1[(1*HD+j)*HD + 2*i+1] * L2E };
    sn2[i] = (v2){ whh1[(2*HD+j)*HD + 2*i] * (2*L2E),  whh1[(2*HD+j)*HD + 2*i+1] * (2*L2E) };
    fw2[i] = (v2){ fcw[2*i], fcw[2*i+1] };
  }
  const float brS  = (bih0[j] + bhh0[j]) * L2E;
  const float bzS  = (bih0[HD+j] + bhh0[HD+j]) * L2E;
  const float biS  = bih0[2*HD+j] * (2*L2E);
  const float bhS  = bhh0[2*HD+j] * (2*L2E);
  const float br1S = (bih1[j] + bhh1[j]) * L2E;
  const float bz1S = (bih1[HD+j] + bhh1[HD+j]) * L2E;
  const float bi1S = bih1[2*HD+j] * (2*L2E);
  const float bh1S = bhh1[2*HD+j] * (2*L2E);
  const float fb   = fcb[0];

  v2 hv2[6], hw2[6];                     // h1[t-1], h2[t-1] component pairs
#pragma unroll
  for (int i = 0; i < 6; ++i) { hv2[i] = (v2){0.f, 0.f}; hw2[i] = (v2){0.f, 0.f}; }
  float h1 = 0.f, h2 = 0.f;

  const v2* xp2 = (const v2*)(x + (size_t)b * Tlen * IND);  // 9 v2 per step
  float* outp = out + (size_t)b * Tlen;

  v2 xb0[9], xb1[9];
  v2 Pr2, Pz2, Pn2;
  {
#pragma unroll
    for (int i = 0; i < 9; ++i) xb0[i] = xp2[i];            // x[0]
    Pr2 = (v2){brS, 0.f}; Pz2 = (v2){bzS, 0.f}; Pn2 = (v2){biS, 0.f};
#pragma unroll
    for (int i = 0; i < 9; ++i) {
      Pr2 = pkfma(xb0[i], wr2[i], Pr2);
      Pz2 = pkfma(xb0[i], wz2[i], Pz2);
      Pn2 = pkfma(xb0[i], wn2[i], Pn2);
    }
#pragma unroll
    for (int i = 0; i < 9; ++i) xb1[i] = xp2[9 + i];        // x[1]
#pragma unroll
    for (int i = 0; i < 9; ++i) xb0[i] = xp2[18 + i];       // x[2]
  }

// Entering STEP(T): P = proj(x[T]); XN holds x[T+1]; hv2 = h1[T-1]; hw2 = h2[T-1].
#define STEP(T, XN)                                                           \
  do {                                                                        \
    /* gates0: hh0 dots on hv2 + projections */                               \
    v2 ra2 = Pr2, za2 = Pz2, ha2 = (v2){bhS, 0.f};                            \
    _Pragma("unroll")                                                         \
    for (int i = 0; i < 6; ++i) {                                             \
      ra2 = pkfma(hv2[i], ur2[i], ra2);                                       \
      za2 = pkfma(hv2[i], uz2[i], za2);                                       \
      ha2 = pkfma(hv2[i], un2[i], ha2);                                       \
    }                                                                         \
    {                                                                         \
      float ar = ra2.x + ra2.y, az = za2.x + za2.y;                           \
      float hn = ha2.x + ha2.y, an = Pn2.x + Pn2.y;                           \
      float r = sigmoid_s(ar), zg = sigmoid_s(az);                            \
      float n = tanh_s(an + r * hn);                                          \
      h1 = n + zg * (h1 - n);                                                 \
    }                                                                         \
    sp[lane15] = h1;   /* slots 12-15 hold clamped row 11, never read */      \
    v4f a0 = ((const v4f*)sp)[0];   /* readback issued right after write */   \
    v4f a1 = ((const v4f*)sp)[1];                                             \
    v4f a2 = ((const v4f*)sp)[2];                                             \
    /* cover 1: hh1 + FC dots on hw2 = h2[T-1] (independent) */               \
    v2 rb = (v2){br1S, 0.f}, zb = (v2){bz1S, 0.f};                            \
    v2 hb = (v2){bh1S, 0.f}, ob = (v2){fb, 0.f};                              \
    _Pragma("unroll")                                                         \
    for (int i = 0; i < 6; ++i) {                                             \
      rb = pkfma(hw2[i], sr2[i], rb); zb = pkfma(hw2[i], sz2[i], zb);         \
      hb = pkfma(hw2[i], sn2[i], hb); ob = pkfma(hw2[i], fw2[i], ob);         \
    }                                                                         \
    if ((T) > 0 && lane15 == 0) outp[(T) - 1] = ob.x + ob.y;                  \
    /* cover 2: projections of x[T+1] (independent) */                        \
    Pr2 = (v2){brS, 0.f}; Pz2 = (v2){bzS, 0.f}; Pn2 = (v2){biS, 0.f};         \
    _Pragma("unroll")                                                         \
    for (int i = 0; i < 9; ++i) {                                             \
      Pr2 = pkfma(XN[i], wr2[i], Pr2);                                        \
      Pz2 = pkfma(XN[i], wz2[i], Pz2);                                        \
      Pn2 = pkfma(XN[i], wn2[i], Pn2);                                        \
    }                                                                         \
    if ((T) + 3 < Tlen) {   /* x prefetch, 3 steps ahead */                   \
      const v2* p_ = xp2 + (size_t)((T) + 3) * 9;                             \
      _Pragma("unroll")                                                       \
      for (int i = 0; i < 9; ++i) XN[i] = p_[i];                              \
    }                                                                         \
    /* consume h1[T] readback */                                              \
    hv2[0] = vlo(a0); hv2[1] = vhi(a0);                                       \
    hv2[2] = vlo(a1); hv2[3] = vhi(a1);                                       \
    hv2[4] = vlo(a2); hv2[5] = vhi(a2);                                       \
    /* ih1 dots on fresh h1[T] */                                             \
    v2 ib = (v2){bi1S, 0.f};                                                  \
    _Pragma("unroll")                                                         \
    for (int i = 0; i < 6; ++i) {                                             \
      rb = pkfma(hv2[i], vr2[i], rb);                                         \
      zb = pkfma(hv2[i], vz2[i], zb);                                         \
      ib = pkfma(hv2[i], vn2[i], ib);                                         \
    }                                                                         \
    {                                                                         \
      float ar = rb.x + rb.y, az = zb.x + zb.y;                               \
      float hn = hb.x + hb.y, an = ib.x + ib.y;                               \
      float r = sigmoid_s(ar), zg = sigmoid_s(az);                            \
      float n = tanh_s(an + r * hn);                                          \
      h2 = n + zg * (h2 - n);                                                 \
    }                                                                         \
    sq[lane15] = h2;                                                          \
    v4f c0 = ((const v4f*)sq)[0];  /* consumed next step at hh1 (covered) */  \
    v4f c1 = ((const v4f*)sq)[1];                                             \
    v4f c2 = ((const v4f*)sq)[2];                                             \
    hw2[0] = vlo(c0); hw2[1] = vhi(c0);                                       \
    hw2[2] = vlo(c1); hw2[3] = vhi(c1);                                       \
    hw2[4] = vlo(c2); hw2[5] = vhi(c2);                                       \
  } while (0)

  for (int t = 0; t < Tlen; t += 2) {
    STEP(t, xb1);
    STEP(t + 1, xb0);
  }
#undef STEP

  // epilogue: FC on h2[Tlen-1]
  v2 ob = (v2){fb, 0.f};
#pragma unroll
  for (int i = 0; i < 6; ++i) ob = pkfma(hw2[i], fw2[i], ob);
  if (lane15 == 0) outp[Tlen - 1] = ob.x + ob.y;
}

extern "C" void kernel_launch(void* const* d_in, const int* in_sizes, int n_in,
                              void* d_out, int out_size, void* d_ws, size_t ws_size,
                              hipStream_t stream) {
  (void)in_sizes; (void)n_in; (void)d_ws; (void)ws_size; (void)out_size;
  const float* x    = (const float*)d_in[0];
  const float* wih0 = (const float*)d_in[1];
  const float* whh0 = (const float*)d_in[2];
  const float* bih0 = (const float*)d_in[3];
  const float* bhh0 = (const float*)d_in[4];
  const float* wih1 = (const float*)d_in[5];
  const float* whh1 = (const float*)d_in[6];
  const float* bih1 = (const float*)d_in[7];
  const float* bhh1 = (const float*)d_in[8];
  const float* fcw  = (const float*)d_in[9];
  const float* fcb  = (const float*)d_in[10];
  float* out = (float*)d_out;

  hipLaunchKernelGGL(gru2_merged, dim3(Bsz / 16), dim3(256), 0, stream,
                     x, wih0, whh0, bih0, bhh0, wih1, whh1, bih1, bhh1, fcw, fcb, out);
}

// Round 13
// 202.121 us; speedup vs baseline: 1.3191x; 1.3191x over previous
//
#include <hip/hip_runtime.h>

#define Bsz 4096
#define Tlen 512
#define IND 18
#define HD 12
#define L2E 1.44269504088896340736f

typedef float v2 __attribute__((ext_vector_type(2)));
typedef float v4f __attribute__((ext_vector_type(4)));

__device__ __forceinline__ v2 pkfma(v2 a, v2 b, v2 c) {
  return __builtin_elementwise_fma(a, b, c);  // v_pk_fma_f32
}
__device__ __forceinline__ v2 vlo(v4f a) { return (v2){a.x, a.y}; }
__device__ __forceinline__ v2 vhi(v4f a) { return (v2){a.z, a.w}; }
// args pre-scaled: sigmoid arg by log2e, tanh arg by 2*log2e (folded into weights)
__device__ __forceinline__ float sigmoid_s(float x) {
  return __builtin_amdgcn_rcpf(1.f + __builtin_amdgcn_exp2f(-x));
}
__device__ __forceinline__ float tanh_s(float x) {
  return 1.f - 2.f * __builtin_amdgcn_rcpf(1.f + __builtin_amdgcn_exp2f(x));
}

// 3-wave specialization, 4 steps per barrier tick (130 ticks):
//   wave 0 (A): layer-0 recurrence (hh0 + gates) — consumes gi0, produces h1
//   wave 1 (B): layer-1 + FC (round-11 code, one tick later) — consumes h1
//   wave 2 (C): x-projections gi0 = W_ih0·x (no recurrence) — one tick ahead
// Block = 192 threads, 4 batches (16 lanes each, full dots in-lane).
// 1024 blocks * 3 waves = 3072 waves = 3 waves/SIMD; HW round-robin puts one
// A, one B, one C (from different blocks -> staggered phases) on each SIMD.
// gi0: C->A and h1: A->B via tick-parity double-buffered LDS.
extern "C" __global__ void __launch_bounds__(192, 3) gru2_abc(
    const float* __restrict__ x,
    const float* __restrict__ wih0, const float* __restrict__ whh0,
    const float* __restrict__ bih0, const float* __restrict__ bhh0,
    const float* __restrict__ wih1, const float* __restrict__ whh1,
    const float* __restrict__ bih1, const float* __restrict__ bhh1,
    const float* __restrict__ fcw, const float* __restrict__ fcb,
    float* __restrict__ out)
{
  const int tid    = threadIdx.x;
  const int lane15 = tid & 15;
  const int g      = (tid >> 4) & 3;     // batch within block (0..3)
  const int wt     = tid >> 6;           // 0=A, 1=B, 2=C
  const int b      = blockIdx.x * 4 + g;
  const int j      = (lane15 < HD) ? lane15 : (HD - 1);

  __shared__ float gi0buf[2][4][4][48];  // [par][step][batch][gate*16 + row]
  __shared__ float h1buf[2][4][4][16];   // [par][step][batch][row]
  __shared__ float h2buf[4][16];         // B-private broadcast slot

#define BAR()                                           \
  do {                                                  \
    asm volatile("s_waitcnt lgkmcnt(0)" ::: "memory");  \
    __builtin_amdgcn_s_barrier();                       \
    asm volatile("" ::: "memory");                      \
  } while (0)

  if (wt == 2) {
    // ---------------- C: gi0 projections, one tick ahead ----------------
    v2 wr2[9], wz2[9], wn2[9];
#pragma unroll
    for (int i = 0; i < 9; ++i) {
      wr2[i] = (v2){ wih0[(0*HD+j)*IND + 2*i] * L2E,       wih0[(0*HD+j)*IND + 2*i+1] * L2E };
      wz2[i] = (v2){ wih0[(1*HD+j)*IND + 2*i] * L2E,       wih0[(1*HD+j)*IND + 2*i+1] * L2E };
      wn2[i] = (v2){ wih0[(2*HD+j)*IND + 2*i] * (2*L2E),   wih0[(2*HD+j)*IND + 2*i+1] * (2*L2E) };
    }
    const float brS = (bih0[j] + bhh0[j]) * L2E;
    const float bzS = (bih0[HD+j] + bhh0[HD+j]) * L2E;
    const float biS = bih0[2*HD+j] * (2*L2E);

    const v2* xp2 = (const v2*)(x + (size_t)b * Tlen * IND);  // 9 v2 per step
    v2 xb0[9], xb1[9];
#pragma unroll
    for (int i = 0; i < 9; ++i) xb0[i] = xp2[i];       // x[0]
#pragma unroll
    for (int i = 0; i < 9; ++i) xb1[i] = xp2[9 + i];   // x[1]

#define CSTEP(S, XB)                                                          \
    do {                                                                      \
      const int t_ = t0 + (S);                                                \
      v2 Pr = (v2){brS, 0.f}, Pz = (v2){bzS, 0.f}, Pn = (v2){biS, 0.f};       \
      _Pragma("unroll")                                                       \
      for (int i = 0; i < 9; ++i) {                                           \
        Pr = pkfma(XB[i], wr2[i], Pr);                                        \
        Pz = pkfma(XB[i], wz2[i], Pz);                                        \
        Pn = pkfma(XB[i], wn2[i], Pn);                                        \
      }                                                                       \
      float* gp = &gi0buf[k & 1][S][g][0];                                    \
      gp[lane15]      = Pr.x + Pr.y;                                          \
      gp[16 + lane15] = Pz.x + Pz.y;                                          \
      gp[32 + lane15] = Pn.x + Pn.y;                                          \
      if (t_ + 2 < Tlen) {   /* 2-step x lookahead */                         \
        const v2* p_ = xp2 + (size_t)(t_ + 2) * 9;                            \
        _Pragma("unroll")                                                     \
        for (int i = 0; i < 9; ++i) XB[i] = p_[i];                            \
      }                                                                       \
    } while (0)

    for (int k = 0; k < 130; ++k) {
      if (k < 128) {
        const int t0 = 4 * k;
        CSTEP(0, xb0);
        CSTEP(1, xb1);
        CSTEP(2, xb0);
        CSTEP(3, xb1);
      }
      BAR();
    }
#undef CSTEP
  } else if (wt == 0) {
    // ---------------- A: layer-0 recurrence (hh0 + gates) ----------------
    v2 ur2[6], uz2[6], un2[6];
#pragma unroll
    for (int i = 0; i < 6; ++i) {
      ur2[i] = (v2){ whh0[(0*HD+j)*HD + 2*i] * L2E,      whh0[(0*HD+j)*HD + 2*i+1] * L2E };
      uz2[i] = (v2){ whh0[(1*HD+j)*HD + 2*i] * L2E,      whh0[(1*HD+j)*HD + 2*i+1] * L2E };
      un2[i] = (v2){ whh0[(2*HD+j)*HD + 2*i] * (2*L2E),  whh0[(2*HD+j)*HD + 2*i+1] * (2*L2E) };
    }
    const float bhS = bhh0[2*HD+j] * (2*L2E);

    v2 hv2[6];
#pragma unroll
    for (int i = 0; i < 6; ++i) hv2[i] = (v2){0.f, 0.f};
    float h1 = 0.f;

    for (int k = 0; k < 130; ++k) {
      if (k >= 1 && k <= 128) {
        const int par = (k - 1) & 1;
        // all 12 gi scalars for the tick up front (ready since last barrier)
        float GR[4], GZ[4], GN[4];
#pragma unroll
        for (int s = 0; s < 4; ++s) {
          const float* gp = &gi0buf[par][s][g][0];
          GR[s] = gp[j]; GZ[s] = gp[16 + j]; GN[s] = gp[32 + j];
        }
#pragma unroll
        for (int s = 0; s < 4; ++s) {
          v2 ra = (v2){GR[s], 0.f}, za = (v2){GZ[s], 0.f}, ha = (v2){bhS, 0.f};
#pragma unroll
          for (int i = 0; i < 6; ++i) {
            ra = pkfma(hv2[i], ur2[i], ra);
            za = pkfma(hv2[i], uz2[i], za);
            ha = pkfma(hv2[i], un2[i], ha);
          }
          float ar = ra.x + ra.y, az = za.x + za.y, hn = ha.x + ha.y;
          float r = sigmoid_s(ar), zg = sigmoid_s(az);
          float n = tanh_s(GN[s] + r * hn);
          h1 = n + zg * (h1 - n);
          float* sp = &h1buf[par][s][g][0];
          sp[lane15] = h1;   // slots 12-15 hold clamped row 11, never read
          v4f a0 = ((const v4f*)sp)[0];
          v4f a1 = ((const v4f*)sp)[1];
          v4f a2 = ((const v4f*)sp)[2];
          hv2[0] = vlo(a0); hv2[1] = vhi(a0);
          hv2[2] = vlo(a1); hv2[3] = vhi(a1);
          hv2[4] = vlo(a2); hv2[5] = vhi(a2);
        }
      }
      BAR();
    }
  } else {
    // ---------------- B: layer 1 + FC (two ticks behind C) ----------------
    v2 vr2[6], vz2[6], vn2[6];           // ih1 (scaled)
    v2 sr2[6], sz2[6], sn2[6];           // hh1 (scaled)
    v2 fw2[6];                           // fc (unscaled)
#pragma unroll
    for (int i = 0; i < 6; ++i) {
      vr2[i] = (v2){ wih1[(0*HD+j)*HD + 2*i] * L2E,      wih1[(0*HD+j)*HD + 2*i+1] * L2E };
      vz2[i] = (v2){ wih1[(1*HD+j)*HD + 2*i] * L2E,      wih1[(1*HD+j)*HD + 2*i+1] * L2E };
      vn2[i] = (v2){ wih1[(2*HD+j)*HD + 2*i] * (2*L2E),  wih1[(2*HD+j)*HD + 2*i+1] * (2*L2E) };
      sr2[i] = (v2){ whh1[(0*HD+j)*HD + 2*i] * L2E,      whh1[(0*HD+j)*HD + 2*i+1] * L2E };
      sz2[i] = (v2){ whh1[(1*HD+j)*HD + 2*i] * L2E,      whh1[(1*HD+j)*HD + 2*i+1] * L2E };
      sn2[i] = (v2){ whh1[(2*HD+j)*HD + 2*i] * (2*L2E),  whh1[(2*HD+j)*HD + 2*i+1] * (2*L2E) };
      fw2[i] = (v2){ fcw[2*i], fcw[2*i+1] };
    }
    const float br1S = (bih1[j] + bhh1[j]) * L2E;
    const float bz1S = (bih1[HD+j] + bhh1[HD+j]) * L2E;
    const float bi1S = bih1[2*HD+j] * (2*L2E);
    const float bh1S = bhh1[2*HD+j] * (2*L2E);
    const float fb   = fcb[0];

    v2 hw2[6];
#pragma unroll
    for (int i = 0; i < 6; ++i) hw2[i] = (v2){0.f, 0.f};
    float h2 = 0.f;
    float* outp = out + (size_t)b * Tlen;
    float* sq = &h2buf[g][0];

#define READQ(Q, SIDX)                                                        \
    { const float* sp_ = &h1buf[par][SIDX][g][0];                             \
      Q##0 = ((const v4f*)sp_)[0];                                            \
      Q##1 = ((const v4f*)sp_)[1];                                            \
      Q##2 = ((const v4f*)sp_)[2]; }

#define IH1(Q, ra, za, ia)                                                    \
    ra = pkfma(vlo(Q##0), vr2[0], ra); za = pkfma(vlo(Q##0), vz2[0], za); ia = pkfma(vlo(Q##0), vn2[0], ia); \
    ra = pkfma(vhi(Q##0), vr2[1], ra); za = pkfma(vhi(Q##0), vz2[1], za); ia = pkfma(vhi(Q##0), vn2[1], ia); \
    ra = pkfma(vlo(Q##1), vr2[2], ra); za = pkfma(vlo(Q##1), vz2[2], za); ia = pkfma(vlo(Q##1), vn2[2], ia); \
    ra = pkfma(vhi(Q##1), vr2[3], ra); za = pkfma(vhi(Q##1), vz2[3], za); ia = pkfma(vhi(Q##1), vn2[3], ia); \
    ra = pkfma(vlo(Q##2), vr2[4], ra); za = pkfma(vlo(Q##2), vz2[4], za); ia = pkfma(vlo(Q##2), vn2[4], ia); \
    ra = pkfma(vhi(Q##2), vr2[5], ra); za = pkfma(vhi(Q##2), vz2[5], za); ia = pkfma(vhi(Q##2), vn2[5], ia);

#define HH1FC(ra, za, ha, oa)                                                 \
    _Pragma("unroll")                                                         \
    for (int i = 0; i < 6; ++i) {                                             \
      ra = pkfma(hw2[i], sr2[i], ra); za = pkfma(hw2[i], sz2[i], za);         \
      ha = pkfma(hw2[i], sn2[i], ha); oa = pkfma(hw2[i], fw2[i], oa);         \
    }

#define BTAIL(ra, za, ha, ia)                                                 \
    { float ar_ = ra.x + ra.y, az_ = za.x + za.y;                             \
      float hn_ = ha.x + ha.y, an_ = ia.x + ia.y;                             \
      float r_ = sigmoid_s(ar_), zg_ = sigmoid_s(az_);                        \
      float n_ = tanh_s(an_ + r_ * hn_);                                      \
      h2 = n_ + zg_ * (h2 - n_);                                              \
      sq[lane15] = h2;                                                        \
      v4f c0_ = ((const v4f*)sq)[0];                                          \
      v4f c1_ = ((const v4f*)sq)[1];                                          \
      v4f c2_ = ((const v4f*)sq)[2];                                          \
      hw2[0] = vlo(c0_); hw2[1] = vhi(c0_); hw2[2] = vlo(c1_);                \
      hw2[3] = vhi(c1_); hw2[4] = vlo(c2_); hw2[5] = vhi(c2_); }

    for (int k = 0; k < 130; ++k) {
      if (k >= 2) {
        const int par = (k - 2) & 1;
        const int s0 = 4 * (k - 2);
        v4f qa0, qa1, qa2, qb0, qb1, qb2;
        READQ(qa, 0)
        READQ(qb, 1)
        float o0, o1, o2, o3;
        { // S=0: hh1+FC first (hw2 landed a barrier ago) -> covers qa reads
          v2 ra = (v2){br1S, 0.f}, za = (v2){bz1S, 0.f};
          v2 ha = (v2){bh1S, 0.f}, oa = (v2){fb, 0.f};
          HH1FC(ra, za, ha, oa)
          o0 = oa.x + oa.y;
          v2 ia = (v2){bi1S, 0.f};
          IH1(qa, ra, za, ia)
          BTAIL(ra, za, ha, ia)
        }
        READQ(qa, 2)   // prefetch h1 for S=2
        { // S=1: ih1 first -> covers S=0's h2 readback
          v2 ra = (v2){br1S, 0.f}, za = (v2){bz1S, 0.f}, ia = (v2){bi1S, 0.f};
          IH1(qb, ra, za, ia)
          v2 ha = (v2){bh1S, 0.f}, oa = (v2){fb, 0.f};
          HH1FC(ra, za, ha, oa)
          o1 = oa.x + oa.y;
          BTAIL(ra, za, ha, ia)
        }
        READQ(qb, 3)   // prefetch h1 for S=3
        { // S=2
          v2 ra = (v2){br1S, 0.f}, za = (v2){bz1S, 0.f}, ia = (v2){bi1S, 0.f};
          IH1(qa, ra, za, ia)
          v2 ha = (v2){bh1S, 0.f}, oa = (v2){fb, 0.f};
          HH1FC(ra, za, ha, oa)
          o2 = oa.x + oa.y;
          BTAIL(ra, za, ha, ia)
        }
        { // S=3
          v2 ra = (v2){br1S, 0.f}, za = (v2){bz1S, 0.f}, ia = (v2){bi1S, 0.f};
          IH1(qb, ra, za, ia)
          v2 ha = (v2){bh1S, 0.f}, oa = (v2){fb, 0.f};
          HH1FC(ra, za, ha, oa)
          o3 = oa.x + oa.y;
          BTAIL(ra, za, ha, ia)
        }
        if (lane15 == 0) {   // one exec toggle per tick
          if (k >= 3) outp[s0 - 1] = o0;
          outp[s0] = o1; outp[s0 + 1] = o2; outp[s0 + 2] = o3;
        }
      }
      BAR();
    }
#undef READQ
#undef IH1
#undef HH1FC
#undef BTAIL
    // epilogue: FC on h2[Tlen-1]
    v2 oa = (v2){fb, 0.f};
#pragma unroll
    for (int i = 0; i < 6; ++i) oa = pkfma(hw2[i], fw2[i], oa);
    if (lane15 == 0) outp[Tlen - 1] = oa.x + oa.y;
  }
#undef BAR
}

extern "C" void kernel_launch(void* const* d_in, const int* in_sizes, int n_in,
                              void* d_out, int out_size, void* d_ws, size_t ws_size,
                              hipStream_t stream) {
  (void)in_sizes; (void)n_in; (void)d_ws; (void)ws_size; (void)out_size;
  const float* x    = (const float*)d_in[0];
  const float* wih0 = (const float*)d_in[1];
  const float* whh0 = (const float*)d_in[2];
  const float* bih0 = (const float*)d_in[3];
  const float* bhh0 = (const float*)d_in[4];
  const float* wih1 = (const float*)d_in[5];
  const float* whh1 = (const float*)d_in[6];
  const float* bih1 = (const float*)d_in[7];
  const float* bhh1 = (const float*)d_in[8];
  const float* fcw  = (const float*)d_in[9];
  const float* fcb  = (const float*)d_in[10];
  float* out = (float*)d_out;

  hipLaunchKernelGGL(gru2_abc, dim3(Bsz / 4), dim3(192), 0, stream,
                     x, wih0, whh0, bih0, bhh0, wih1, whh1, bih1, bhh1, fcw, fcb, out);
}

// Round 14
// 185.433 us; speedup vs baseline: 1.4378x; 1.0900x over previous
//
#include <hip/hip_runtime.h>

#define Bsz 4096
#define Tlen 512
#define IND 18
#define HD 12
#define L2E 1.44269504088896340736f

typedef float v2 __attribute__((ext_vector_type(2)));
typedef float v4f __attribute__((ext_vector_type(4)));

__device__ __forceinline__ v2 pkfma(v2 a, v2 b, v2 c) {
  return __builtin_elementwise_fma(a, b, c);  // v_pk_fma_f32
}
__device__ __forceinline__ v2 vlo(v4f a) { return (v2){a.x, a.y}; }
__device__ __forceinline__ v2 vhi(v4f a) { return (v2){a.z, a.w}; }
// args pre-scaled: sigmoid arg by log2e, tanh arg by 2*log2e (folded into weights)
__device__ __forceinline__ float sigmoid_s(float x) {
  return __builtin_amdgcn_rcpf(1.f + __builtin_amdgcn_exp2f(-x));
}
__device__ __forceinline__ float tanh_s(float x) {
  return 1.f - 2.f * __builtin_amdgcn_rcpf(1.f + __builtin_amdgcn_exp2f(x));
}

// Round-11 producer/consumer pipeline with 8 timesteps per barrier tick
// (65 barriers vs 129): A (layer 0) / B (layer 1 + FC) waves, 4 batches per
// 128-thread block, packed v_pk_fma_f32 dots, exp2-prescaled weights.
// x rows loaded as dwordx4 (5 loads/step instead of 9).
// 1024 blocks * 2 waves = 2048 waves = 2 waves/SIMD.
extern "C" __global__ void __launch_bounds__(128, 2) gru2_pipe8(
    const float* __restrict__ x,
    const float* __restrict__ wih0, const float* __restrict__ whh0,
    const float* __restrict__ bih0, const float* __restrict__ bhh0,
    const float* __restrict__ wih1, const float* __restrict__ whh1,
    const float* __restrict__ bih1, const float* __restrict__ bhh1,
    const float* __restrict__ fcw, const float* __restrict__ fcb,
    float* __restrict__ out)
{
  const int tid    = threadIdx.x;
  const int lane15 = tid & 15;
  const int g      = (tid >> 4) & 3;     // batch within block (0..3)
  const bool isA   = (tid >> 6) == 0;
  const int b      = blockIdx.x * 4 + g;
  const int j      = (lane15 < HD) ? lane15 : (HD - 1);

  __shared__ float h1buf[2][8][4][16];   // [tick parity][step-in-tick][batch][row]
  __shared__ float h2buf[4][16];         // B-private broadcast slot

#define BAR()                                           \
  do {                                                  \
    asm volatile("s_waitcnt lgkmcnt(0)" ::: "memory");  \
    __builtin_amdgcn_s_barrier();                       \
    asm volatile("" ::: "memory");                      \
  } while (0)

  if (isA) {
    // ---------------- A: layer 0, steps 8k..8k+7 per tick ----------------
    v2 wr2[9], wz2[9], wn2[9];           // ih0 rows j/12+j/24+j, k-pairs (scaled)
#pragma unroll
    for (int i = 0; i < 9; ++i) {
      wr2[i] = (v2){ wih0[(0*HD+j)*IND + 2*i] * L2E,       wih0[(0*HD+j)*IND + 2*i+1] * L2E };
      wz2[i] = (v2){ wih0[(1*HD+j)*IND + 2*i] * L2E,       wih0[(1*HD+j)*IND + 2*i+1] * L2E };
      wn2[i] = (v2){ wih0[(2*HD+j)*IND + 2*i] * (2*L2E),   wih0[(2*HD+j)*IND + 2*i+1] * (2*L2E) };
    }
    v2 ur2[6], uz2[6], un2[6];           // hh0 (scaled)
#pragma unroll
    for (int i = 0; i < 6; ++i) {
      ur2[i] = (v2){ whh0[(0*HD+j)*HD + 2*i] * L2E,      whh0[(0*HD+j)*HD + 2*i+1] * L2E };
      uz2[i] = (v2){ whh0[(1*HD+j)*HD + 2*i] * L2E,      whh0[(1*HD+j)*HD + 2*i+1] * L2E };
      un2[i] = (v2){ whh0[(2*HD+j)*HD + 2*i] * (2*L2E),  whh0[(2*HD+j)*HD + 2*i+1] * (2*L2E) };
    }
    const float brS = (bih0[j] + bhh0[j]) * L2E;
    const float bzS = (bih0[HD+j] + bhh0[HD+j]) * L2E;
    const float biS = bih0[2*HD+j] * (2*L2E);
    const float bhS = bhh0[2*HD+j] * (2*L2E);

    v2 hv2[6];
#pragma unroll
    for (int i = 0; i < 6; ++i) hv2[i] = (v2){0.f, 0.f};
    float h1 = 0.f;

    const float* xbase = x + (size_t)b * Tlen * IND;  // 18 floats per step

    // x buffers: 4 dwordx4 + 1 dwordx2 per row (dword-aligned dwordx4 is legal)
    v4f xA0, xA1, xA2, xA3; v2 xA4;
    v4f xB0, xB1, xB2, xB3; v2 xB4;
    v2 Pr2, Pz2, Pn2;

#define LOADX(XD, T)                                                          \
    { const float* p_ = xbase + (size_t)(T) * IND;                            \
      XD##0 = ((const v4f*)p_)[0]; XD##1 = ((const v4f*)p_)[1];               \
      XD##2 = ((const v4f*)p_)[2]; XD##3 = ((const v4f*)p_)[3];               \
      XD##4 = ((const v2*)p_)[8]; }

#define PROJ(XD)                                                              \
    do {                                                                      \
      Pr2 = (v2){brS, 0.f}; Pz2 = (v2){bzS, 0.f}; Pn2 = (v2){biS, 0.f};       \
      v2 u0 = vlo(XD##0), u1 = vhi(XD##0), u2 = vlo(XD##1), u3 = vhi(XD##1);  \
      v2 u4 = vlo(XD##2), u5 = vhi(XD##2), u6 = vlo(XD##3), u7 = vhi(XD##3);  \
      Pr2=pkfma(u0,wr2[0],Pr2); Pz2=pkfma(u0,wz2[0],Pz2); Pn2=pkfma(u0,wn2[0],Pn2); \
      Pr2=pkfma(u1,wr2[1],Pr2); Pz2=pkfma(u1,wz2[1],Pz2); Pn2=pkfma(u1,wn2[1],Pn2); \
      Pr2=pkfma(u2,wr2[2],Pr2); Pz2=pkfma(u2,wz2[2],Pz2); Pn2=pkfma(u2,wn2[2],Pn2); \
      Pr2=pkfma(u3,wr2[3],Pr2); Pz2=pkfma(u3,wz2[3],Pz2); Pn2=pkfma(u3,wn2[3],Pn2); \
      Pr2=pkfma(u4,wr2[4],Pr2); Pz2=pkfma(u4,wz2[4],Pz2); Pn2=pkfma(u4,wn2[4],Pn2); \
      Pr2=pkfma(u5,wr2[5],Pr2); Pz2=pkfma(u5,wz2[5],Pz2); Pn2=pkfma(u5,wn2[5],Pn2); \
      Pr2=pkfma(u6,wr2[6],Pr2); Pz2=pkfma(u6,wz2[6],Pz2); Pn2=pkfma(u6,wn2[6],Pn2); \
      Pr2=pkfma(u7,wr2[7],Pr2); Pz2=pkfma(u7,wz2[7],Pz2); Pn2=pkfma(u7,wn2[7],Pn2); \
      Pr2=pkfma(XD##4,wr2[8],Pr2); Pz2=pkfma(XD##4,wz2[8],Pz2); Pn2=pkfma(XD##4,wn2[8],Pn2); \
    } while (0)

    LOADX(xA, 0);
    PROJ(xA);          // P = proj(x[0])
    LOADX(xB, 1);
    LOADX(xA, 2);

// Entering ASTEP(T, XN): P = proj(x[T]); XN holds x[T+1].
#define ASTEP(T, XN)                                                          \
    do {                                                                      \
      v2 ra2 = Pr2, za2 = Pz2, ha2 = (v2){bhS, 0.f};                          \
      _Pragma("unroll")                                                       \
      for (int i = 0; i < 6; ++i) {                                           \
        ra2 = pkfma(hv2[i], ur2[i], ra2);                                     \
        za2 = pkfma(hv2[i], uz2[i], za2);                                     \
        ha2 = pkfma(hv2[i], un2[i], ha2);                                     \
      }                                                                       \
      float ar = ra2.x + ra2.y, az = za2.x + za2.y;                           \
      float hn = ha2.x + ha2.y, an = Pn2.x + Pn2.y;                           \
      float r = sigmoid_s(ar), zg = sigmoid_s(az);                            \
      float n = tanh_s(an + r * hn);                                          \
      h1 = n + zg * (h1 - n);                                                 \
      float* sp = &h1buf[k & 1][(T) & 7][g][0];                               \
      sp[lane15] = h1;      /* slots 12-15 hold clamped row 11, never read */ \
      v4f a0 = ((const v4f*)sp)[0];   /* readback issued right after write */ \
      v4f a1 = ((const v4f*)sp)[1];                                           \
      v4f a2 = ((const v4f*)sp)[2];                                           \
      PROJ(XN);  /* next-step projections cover the ds_read latency */        \
      if ((T) + 3 < Tlen) LOADX(XN, (T) + 3);                                 \
      hv2[0] = vlo(a0); hv2[1] = vhi(a0);                                     \
      hv2[2] = vlo(a1); hv2[3] = vhi(a1);                                     \
      hv2[4] = vlo(a2); hv2[5] = vhi(a2);                                     \
    } while (0)

    for (int k = 0; k < 65; ++k) {
      if (k < 64) {
        const int t0 = 8 * k;
        ASTEP(t0 + 0, xB);
        ASTEP(t0 + 1, xA);
        ASTEP(t0 + 2, xB);
        ASTEP(t0 + 3, xA);
        ASTEP(t0 + 4, xB);
        ASTEP(t0 + 5, xA);
        ASTEP(t0 + 6, xB);
        ASTEP(t0 + 7, xA);
      }
      BAR();
    }
#undef ASTEP
#undef PROJ
#undef LOADX
  } else {
    // ---------------- B: layer 1 + FC, steps 8(k-1)..8(k-1)+7 ----------------
    v2 vr2[6], vz2[6], vn2[6];           // ih1 (scaled)
    v2 sr2[6], sz2[6], sn2[6];           // hh1 (scaled)
    v2 fw2[6];                           // fc (unscaled)
#pragma unroll
    for (int i = 0; i < 6; ++i) {
      vr2[i] = (v2){ wih1[(0*HD+j)*HD + 2*i] * L2E,      wih1[(0*HD+j)*HD + 2*i+1] * L2E };
      vz2[i] = (v2){ wih1[(1*HD+j)*HD + 2*i] * L2E,      wih1[(1*HD+j)*HD + 2*i+1] * L2E };
      vn2[i] = (v2){ wih1[(2*HD+j)*HD + 2*i] * (2*L2E),  wih1[(2*HD+j)*HD + 2*i+1] * (2*L2E) };
      sr2[i] = (v2){ whh1[(0*HD+j)*HD + 2*i] * L2E,      whh1[(0*HD+j)*HD + 2*i+1] * L2E };
      sz2[i] = (v2){ whh1[(1*HD+j)*HD + 2*i] * L2E,      whh1[(1*HD+j)*HD + 2*i+1] * L2E };
      sn2[i] = (v2){ whh1[(2*HD+j)*HD + 2*i] * (2*L2E),  whh1[(2*HD+j)*HD + 2*i+1] * (2*L2E) };
      fw2[i] = (v2){ fcw[2*i], fcw[2*i+1] };
    }
    const float br1S = (bih1[j] + bhh1[j]) * L2E;
    const float bz1S = (bih1[HD+j] + bhh1[HD+j]) * L2E;
    const float bi1S = bih1[2*HD+j] * (2*L2E);
    const float bh1S = bhh1[2*HD+j] * (2*L2E);
    const float fb   = fcb[0];

    v2 hw2[6];
#pragma unroll
    for (int i = 0; i < 6; ++i) hw2[i] = (v2){0.f, 0.f};
    float h2 = 0.f;
    float* outp = out + (size_t)b * Tlen;
    float* sq = &h2buf[g][0];

#define READQ(Q, SIDX)                                                        \
    { const float* sp_ = &h1buf[par][SIDX][g][0];                             \
      Q##0 = ((const v4f*)sp_)[0];                                            \
      Q##1 = ((const v4f*)sp_)[1];                                            \
      Q##2 = ((const v4f*)sp_)[2]; }

#define IH1(Q, ra, za, ia)                                                    \
    ra = pkfma(vlo(Q##0), vr2[0], ra); za = pkfma(vlo(Q##0), vz2[0], za); ia = pkfma(vlo(Q##0), vn2[0], ia); \
    ra = pkfma(vhi(Q##0), vr2[1], ra); za = pkfma(vhi(Q##0), vz2[1], za); ia = pkfma(vhi(Q##0), vn2[1], ia); \
    ra = pkfma(vlo(Q##1), vr2[2], ra); za = pkfma(vlo(Q##1), vz2[2], za); ia = pkfma(vlo(Q##1), vn2[2], ia); \
    ra = pkfma(vhi(Q##1), vr2[3], ra); za = pkfma(vhi(Q##1), vz2[3], za); ia = pkfma(vhi(Q##1), vn2[3], ia); \
    ra = pkfma(vlo(Q##2), vr2[4], ra); za = pkfma(vlo(Q##2), vz2[4], za); ia = pkfma(vlo(Q##2), vn2[4], ia); \
    ra = pkfma(vhi(Q##2), vr2[5], ra); za = pkfma(vhi(Q##2), vz2[5], za); ia = pkfma(vhi(Q##2), vn2[5], ia);

#define HH1FC(ra, za, ha, oa)                                                 \
    _Pragma("unroll")                                                         \
    for (int i = 0; i < 6; ++i) {                                             \
      ra = pkfma(hw2[i], sr2[i], ra); za = pkfma(hw2[i], sz2[i], za);         \
      ha = pkfma(hw2[i], sn2[i], ha); oa = pkfma(hw2[i], fw2[i], oa);         \
    }

#define BTAIL(ra, za, ha, ia)                                                 \
    { float ar_ = ra.x + ra.y, az_ = za.x + za.y;                             \
      float hn_ = ha.x + ha.y, an_ = ia.x + ia.y;                             \
      float r_ = sigmoid_s(ar_), zg_ = sigmoid_s(az_);                        \
      float n_ = tanh_s(an_ + r_ * hn_);                                      \
      h2 = n_ + zg_ * (h2 - n_);                                              \
      sq[lane15] = h2;                                                        \
      v4f c0_ = ((const v4f*)sq)[0];                                          \
      v4f c1_ = ((const v4f*)sq)[1];                                          \
      v4f c2_ = ((const v4f*)sq)[2];                                          \
      hw2[0] = vlo(c0_); hw2[1] = vhi(c0_); hw2[2] = vlo(c1_);                \
      hw2[3] = vhi(c1_); hw2[4] = vlo(c2_); hw2[5] = vhi(c2_); }

// steady-state step: ih1 first (covers prev h2 readback), then hh1+FC
#define BSTEP(Q, OVAR)                                                        \
    { v2 ra = (v2){br1S, 0.f}, za = (v2){bz1S, 0.f}, ia = (v2){bi1S, 0.f};    \
      IH1(Q, ra, za, ia)                                                      \
      v2 ha = (v2){bh1S, 0.f}, oa = (v2){fb, 0.f};                            \
      HH1FC(ra, za, ha, oa)                                                   \
      OVAR = oa.x + oa.y;                                                     \
      BTAIL(ra, za, ha, ia) }

    for (int k = 0; k < 65; ++k) {
      if (k >= 1) {
        const int par = (k - 1) & 1;
        const int s0 = 8 * (k - 1);
        v4f qa0, qa1, qa2, qb0, qb1, qb2;
        READQ(qa, 0)
        READQ(qb, 1)
        float o0, o1, o2, o3, o4, o5, o6, o7;
        { // S=0: hh1+FC first (hw2 landed a barrier ago) -> covers qa reads
          v2 ra = (v2){br1S, 0.f}, za = (v2){bz1S, 0.f};
          v2 ha = (v2){bh1S, 0.f}, oa = (v2){fb, 0.f};
          HH1FC(ra, za, ha, oa)
          o0 = oa.x + oa.y;
          v2 ia = (v2){bi1S, 0.f};
          IH1(qa, ra, za, ia)
          BTAIL(ra, za, ha, ia)
        }
        READQ(qa, 2)
        BSTEP(qb, o1)
        READQ(qb, 3)
        BSTEP(qa, o2)
        READQ(qa, 4)
        BSTEP(qb, o3)
        READQ(qb, 5)
        BSTEP(qa, o4)
        READQ(qa, 6)
        BSTEP(qb, o5)
        READQ(qb, 7)
        BSTEP(qa, o6)
        BSTEP(qb, o7)
        if (lane15 == 0) {   // one exec toggle per tick
          if (k >= 2) outp[s0 - 1] = o0;
          outp[s0 + 0] = o1; outp[s0 + 1] = o2; outp[s0 + 2] = o3;
          outp[s0 + 3] = o4; outp[s0 + 4] = o5; outp[s0 + 5] = o6;
          outp[s0 + 6] = o7;
        }
      }
      BAR();
    }
#undef READQ
#undef IH1
#undef HH1FC
#undef BTAIL
#undef BSTEP
    // epilogue: FC on h2[Tlen-1]
    v2 oa = (v2){fb, 0.f};
#pragma unroll
    for (int i = 0; i < 6; ++i) oa = pkfma(hw2[i], fw2[i], oa);
    if (lane15 == 0) outp[Tlen - 1] = oa.x + oa.y;
  }
#undef BAR
}

extern "C" void kernel_launch(void* const* d_in, const int* in_sizes, int n_in,
                              void* d_out, int out_size, void* d_ws, size_t ws_size,
                              hipStream_t stream) {
  (void)in_sizes; (void)n_in; (void)d_ws; (void)ws_size; (void)out_size;
  const float* x    = (const float*)d_in[0];
  const float* wih0 = (const float*)d_in[1];
  const float* whh0 = (const float*)d_in[2];
  const float* bih0 = (const float*)d_in[3];
  const float* bhh0 = (const float*)d_in[4];
  const float* wih1 = (const float*)d_in[5];
  const float* whh1 = (const float*)d_in[6];
  const float* bih1 = (const float*)d_in[7];
  const float* bhh1 = (const float*)d_in[8];
  const float* fcw  = (const float*)d_in[9];
  const float* fcb  = (const float*)d_in[10];
  float* out = (float*)d_out;

  hipLaunchKernelGGL(gru2_pipe8, dim3(Bsz / 4), dim3(128), 0, stream,
                     x, wih0, whh0, bih0, bhh0, wih1, whh1, bih1, bhh1, fcw, fcb, out);
}

// Round 16
// 184.473 us; speedup vs baseline: 1.4453x; 1.0052x over previous
//
#include <hip/hip_runtime.h>

#define Bsz 4096
#define Tlen 512
#define IND 18
#define HD 12
#define L2E 1.44269504088896340736f

typedef float v2 __attribute__((ext_vector_type(2)));
typedef _Float16 h2t __attribute__((ext_vector_type(2)));
typedef _Float16 h4t __attribute__((ext_vector_type(4)));

#if defined(__has_builtin) && __has_builtin(__builtin_amdgcn_fdot2)
__device__ __forceinline__ float fdot2(h2t a, h2t b, float c) {
  return __builtin_amdgcn_fdot2(a, b, c, false);   // v_dot2_f32_f16
}
#else
__device__ __forceinline__ float fdot2(h2t a, h2t b, float c) {
  return fmaf((float)a[0], (float)b[0], fmaf((float)a[1], (float)b[1], c));
}
#endif

__device__ __forceinline__ h2t cvt2h(float a, float b) {
  return __builtin_bit_cast(h2t, __builtin_amdgcn_cvt_pkrtz(a, b));  // v_cvt_pkrtz_f16_f32
}

// args pre-scaled: sigmoid arg by log2e, tanh arg by 2*log2e (folded into weights)
__device__ __forceinline__ float sigmoid_s(float x) {
  return __builtin_amdgcn_rcpf(1.f + __builtin_amdgcn_exp2f(-x));
}
__device__ __forceinline__ float tanh_s(float x) {
  return 1.f - 2.f * __builtin_amdgcn_rcpf(1.f + __builtin_amdgcn_exp2f(x));
}
__device__ __forceinline__ h2t mkw(float a, float b, float s) {
  return (h2t){(_Float16)(a * s), (_Float16)(b * s)};   // RNE weight rounding
}

// Round-11 producer/consumer pipeline (4 steps/tick, 129 barriers) with ALL
// dot products converted to v_dot2_f32_f16: f16 inputs, exact f32 accumulate,
// 2x the FLOP rate of v_pk_fma_f32 and no final pair-reduction. h1/h2 flow
// through LDS as f16 (1 ds_write_b16, pairs land register-aligned for dot2);
// x converts once per step via cvt_pkrtz. Weights f16 (RNE) with exp2
// prescale. 1024 blocks * 2 waves = 2048 waves = 2 waves/SIMD.
extern "C" __global__ void __launch_bounds__(128, 2) gru2_f16dot(
    const float* __restrict__ x,
    const float* __restrict__ wih0, const float* __restrict__ whh0,
    const float* __restrict__ bih0, const float* __restrict__ bhh0,
    const float* __restrict__ wih1, const float* __restrict__ whh1,
    const float* __restrict__ bih1, const float* __restrict__ bhh1,
    const float* __restrict__ fcw, const float* __restrict__ fcb,
    float* __restrict__ out)
{
  const int tid    = threadIdx.x;
  const int lane15 = tid & 15;
  const int g      = (tid >> 4) & 3;     // batch within block (0..3)
  const bool isA   = (tid >> 6) == 0;
  const int b      = blockIdx.x * 4 + g;
  const int j      = (lane15 < HD) ? lane15 : (HD - 1);

  __shared__ _Float16 h1buf[2][4][4][16];   // [parity][step][batch][row], f16
  __shared__ _Float16 h2buf[4][16];         // B-private broadcast slot, f16

#define BAR()                                           \
  do {                                                  \
    asm volatile("s_waitcnt lgkmcnt(0)" ::: "memory");  \
    __builtin_amdgcn_s_barrier();                       \
    asm volatile("" ::: "memory");                      \
  } while (0)

  if (isA) {
    // ---------------- A: layer 0, steps 4k..4k+3 per tick ----------------
    h2t wr2[9], wz2[9], wn2[9];          // ih0 rows j/12+j/24+j, k-pairs
#pragma unroll
    for (int i = 0; i < 9; ++i) {
      wr2[i] = mkw(wih0[(0*HD+j)*IND + 2*i], wih0[(0*HD+j)*IND + 2*i+1], L2E);
      wz2[i] = mkw(wih0[(1*HD+j)*IND + 2*i], wih0[(1*HD+j)*IND + 2*i+1], L2E);
      wn2[i] = mkw(wih0[(2*HD+j)*IND + 2*i], wih0[(2*HD+j)*IND + 2*i+1], 2*L2E);
    }
    h2t ur2[6], uz2[6], un2[6];          // hh0
#pragma unroll
    for (int i = 0; i < 6; ++i) {
      ur2[i] = mkw(whh0[(0*HD+j)*HD + 2*i], whh0[(0*HD+j)*HD + 2*i+1], L2E);
      uz2[i] = mkw(whh0[(1*HD+j)*HD + 2*i], whh0[(1*HD+j)*HD + 2*i+1], L2E);
      un2[i] = mkw(whh0[(2*HD+j)*HD + 2*i], whh0[(2*HD+j)*HD + 2*i+1], 2*L2E);
    }
    const float brS = (bih0[j] + bhh0[j]) * L2E;
    const float bzS = (bih0[HD+j] + bhh0[HD+j]) * L2E;
    const float biS = bih0[2*HD+j] * (2*L2E);
    const float bhS = bhh0[2*HD+j] * (2*L2E);

    h2t hv[6];                           // h1[t-1] row pairs (f16)
#pragma unroll
    for (int i = 0; i < 6; ++i) hv[i] = (h2t){(_Float16)0.f, (_Float16)0.f};
    float h1 = 0.f;

    const v2* xp2 = (const v2*)(x + (size_t)b * Tlen * IND);  // 9 v2 per step
    h2t xb0[9], xb1[9];                  // f16 x pairs
    float Pr, Pz, Pn;

#define LOADCVT(XH, T)                                                        \
    { const v2* p_ = xp2 + (size_t)(T) * 9;                                   \
      _Pragma("unroll")                                                       \
      for (int i = 0; i < 9; ++i) {                                           \
        v2 t_ = p_[i];                                                        \
        XH[i] = cvt2h(t_.x, t_.y);                                            \
      } }

#define PROJ(XH)                                                              \
    do {                                                                      \
      Pr = brS; Pz = bzS; Pn = biS;                                           \
      _Pragma("unroll")                                                       \
      for (int i = 0; i < 9; ++i) {                                           \
        Pr = fdot2(XH[i], wr2[i], Pr);                                        \
        Pz = fdot2(XH[i], wz2[i], Pz);                                        \
        Pn = fdot2(XH[i], wn2[i], Pn);                                        \
      }                                                                       \
    } while (0)

    LOADCVT(xb0, 0);
    PROJ(xb0);         // P = proj(x[0])
    LOADCVT(xb1, 1);
    LOADCVT(xb0, 2);

// Entering ASTEP(T, XN): P = proj(x[T]); XN holds x[T+1]; other buf x[T+2].
#define ASTEP(T, XN)                                                          \
    do {                                                                      \
      float ar = Pr, az = Pz, an = Pn, hn = bhS;                              \
      _Pragma("unroll")                                                       \
      for (int i = 0; i < 6; ++i) {                                           \
        ar = fdot2(hv[i], ur2[i], ar);                                        \
        az = fdot2(hv[i], uz2[i], az);                                        \
        hn = fdot2(hv[i], un2[i], hn);                                        \
      }                                                                       \
      float r = sigmoid_s(ar), zg = sigmoid_s(az);                            \
      float n = tanh_s(an + r * hn);                                          \
      h1 = n + zg * (h1 - n);                                                 \
      _Float16* sp = &h1buf[k & 1][(T) & 3][g][0];                            \
      sp[lane15] = (_Float16)h1;  /* slots 12-15 clamped dup, never read */   \
      h4t q0 = ((const h4t*)sp)[0];   /* readback right after write */        \
      h4t q1 = ((const h4t*)sp)[1];                                           \
      h4t q2 = ((const h4t*)sp)[2];                                           \
      PROJ(XN);   /* next-step projections cover the ds_read latency */       \
      if ((T) + 3 < Tlen) LOADCVT(XN, (T) + 3);                               \
      hv[0] = (h2t){q0[0], q0[1]}; hv[1] = (h2t){q0[2], q0[3]};               \
      hv[2] = (h2t){q1[0], q1[1]}; hv[3] = (h2t){q1[2], q1[3]};               \
      hv[4] = (h2t){q2[0], q2[1]}; hv[5] = (h2t){q2[2], q2[3]};               \
    } while (0)

    for (int k = 0; k < 129; ++k) {
      if (k < 128) {
        const int t0 = 4 * k;
        ASTEP(t0 + 0, xb1);
        ASTEP(t0 + 1, xb0);
        ASTEP(t0 + 2, xb1);
        ASTEP(t0 + 3, xb0);
      }
      BAR();
    }
#undef ASTEP
#undef PROJ
#undef LOADCVT
  } else {
    // ---------------- B: layer 1 + FC, steps 4(k-1)..4(k-1)+3 ----------------
    h2t vr2[6], vz2[6], vn2[6];          // ih1
    h2t sr2[6], sz2[6], sn2[6];          // hh1
    h2t fw2[6];                          // fc (unscaled)
#pragma unroll
    for (int i = 0; i < 6; ++i) {
      vr2[i] = mkw(wih1[(0*HD+j)*HD + 2*i], wih1[(0*HD+j)*HD + 2*i+1], L2E);
      vz2[i] = mkw(wih1[(1*HD+j)*HD + 2*i], wih1[(1*HD+j)*HD + 2*i+1], L2E);
      vn2[i] = mkw(wih1[(2*HD+j)*HD + 2*i], wih1[(2*HD+j)*HD + 2*i+1], 2*L2E);
      sr2[i] = mkw(whh1[(0*HD+j)*HD + 2*i], whh1[(0*HD+j)*HD + 2*i+1], L2E);
      sz2[i] = mkw(whh1[(1*HD+j)*HD + 2*i], whh1[(1*HD+j)*HD + 2*i+1], L2E);
      sn2[i] = mkw(whh1[(2*HD+j)*HD + 2*i], whh1[(2*HD+j)*HD + 2*i+1], 2*L2E);
      fw2[i] = mkw(fcw[2*i], fcw[2*i+1], 1.f);
    }
    const float br1S = (bih1[j] + bhh1[j]) * L2E;
    const float bz1S = (bih1[HD+j] + bhh1[HD+j]) * L2E;
    const float bi1S = bih1[2*HD+j] * (2*L2E);
    const float bh1S = bhh1[2*HD+j] * (2*L2E);
    const float fb   = fcb[0];

    h2t hw[6];                           // h2[t-1] row pairs (f16)
#pragma unroll
    for (int i = 0; i < 6; ++i) hw[i] = (h2t){(_Float16)0.f, (_Float16)0.f};
    float h2 = 0.f;
    float* outp = out + (size_t)b * Tlen;
    _Float16* sq = &h2buf[g][0];

#define READQ(Q, SIDX)                                                        \
    { const _Float16* sp_ = &h1buf[par][SIDX][g][0];                          \
      Q##0 = ((const h4t*)sp_)[0];                                            \
      Q##1 = ((const h4t*)sp_)[1];                                            \
      Q##2 = ((const h4t*)sp_)[2]; }

#define IH1(Q, ra, za, ia)                                                    \
    { h2t p0 = (h2t){Q##0[0], Q##0[1]}, p1 = (h2t){Q##0[2], Q##0[3]};         \
      h2t p2 = (h2t){Q##1[0], Q##1[1]}, p3 = (h2t){Q##1[2], Q##1[3]};         \
      h2t p4 = (h2t){Q##2[0], Q##2[1]}, p5 = (h2t){Q##2[2], Q##2[3]};         \
      ra = fdot2(p0, vr2[0], ra); za = fdot2(p0, vz2[0], za); ia = fdot2(p0, vn2[0], ia); \
      ra = fdot2(p1, vr2[1], ra); za = fdot2(p1, vz2[1], za); ia = fdot2(p1, vn2[1], ia); \
      ra = fdot2(p2, vr2[2], ra); za = fdot2(p2, vz2[2], za); ia = fdot2(p2, vn2[2], ia); \
      ra = fdot2(p3, vr2[3], ra); za = fdot2(p3, vz2[3], za); ia = fdot2(p3, vn2[3], ia); \
      ra = fdot2(p4, vr2[4], ra); za = fdot2(p4, vz2[4], za); ia = fdot2(p4, vn2[4], ia); \
      ra = fdot2(p5, vr2[5], ra); za = fdot2(p5, vz2[5], za); ia = fdot2(p5, vn2[5], ia); }

#define HH1FC(ra, za, ha, oa)                                                 \
    _Pragma("unroll")                                                         \
    for (int i = 0; i < 6; ++i) {                                             \
      ra = fdot2(hw[i], sr2[i], ra); za = fdot2(hw[i], sz2[i], za);           \
      ha = fdot2(hw[i], sn2[i], ha); oa = fdot2(hw[i], fw2[i], oa);           \
    }

#define BTAIL(ra, za, ha, ia)                                                 \
    { float r_ = sigmoid_s(ra), zg_ = sigmoid_s(za);                          \
      float n_ = tanh_s(ia + r_ * ha);                                        \
      h2 = n_ + zg_ * (h2 - n_);                                              \
      sq[lane15] = (_Float16)h2;                                              \
      h4t c0 = ((const h4t*)sq)[0];                                           \
      h4t c1 = ((const h4t*)sq)[1];                                           \
      h4t c2 = ((const h4t*)sq)[2];                                           \
      hw[0] = (h2t){c0[0], c0[1]}; hw[1] = (h2t){c0[2], c0[3]};               \
      hw[2] = (h2t){c1[0], c1[1]}; hw[3] = (h2t){c1[2], c1[3]};               \
      hw[4] = (h2t){c2[0], c2[1]}; hw[5] = (h2t){c2[2], c2[3]}; }

// steady-state step: ih1 first (covers prev h2 readback), then hh1+FC
#define BSTEP(Q, OVAR)                                                        \
    { float ra = br1S, za = bz1S, ia = bi1S;                                  \
      IH1(Q, ra, za, ia)                                                      \
      float ha = bh1S, oa = fb;                                               \
      HH1FC(ra, za, ha, oa)                                                   \
      OVAR = oa;                                                              \
      BTAIL(ra, za, ha, ia) }

    for (int k = 0; k < 129; ++k) {
      if (k >= 1) {
        const int par = (k - 1) & 1;
        const int s0 = 4 * (k - 1);
        h4t qa0, qa1, qa2, qb0, qb1, qb2;
        READQ(qa, 0)
        READQ(qb, 1)
        float o0, o1, o2, o3;
        { // S=0: hh1+FC first (hw landed a barrier ago) -> covers qa reads
          float ra = br1S, za = bz1S, ha = bh1S, oa = fb;
          HH1FC(ra, za, ha, oa)
          o0 = oa;
          float ia = bi1S;
          IH1(qa, ra, za, ia)
          BTAIL(ra, za, ha, ia)
        }
        READQ(qa, 2)   // prefetch h1 for S=2
        BSTEP(qb, o1)
        READQ(qb, 3)   // prefetch h1 for S=3
        BSTEP(qa, o2)
        BSTEP(qb, o3)
        if (lane15 == 0) {   // one exec toggle per tick
          if (k >= 2) outp[s0 - 1] = o0;
          outp[s0] = o1; outp[s0 + 1] = o2; outp[s0 + 2] = o3;
        }
      }
      BAR();
    }
#undef READQ
#undef IH1
#undef HH1FC
#undef BTAIL
#undef BSTEP
    // epilogue: FC on h2[Tlen-1]
    float oa = fb;
#pragma unroll
    for (int i = 0; i < 6; ++i) oa = fdot2(hw[i], fw2[i], oa);
    if (lane15 == 0) outp[Tlen - 1] = oa;
  }
#undef BAR
}

extern "C" void kernel_launch(void* const* d_in, const int* in_sizes, int n_in,
                              void* d_out, int out_size, void* d_ws, size_t ws_size,
                              hipStream_t stream) {
  (void)in_sizes; (void)n_in; (void)d_ws; (void)ws_size; (void)out_size;
  const float* x    = (const float*)d_in[0];
  const float* wih0 = (const float*)d_in[1];
  const float* whh0 = (const float*)d_in[2];
  const float* bih0 = (const float*)d_in[3];
  const float* bhh0 = (const float*)d_in[4];
  const float* wih1 = (const float*)d_in[5];
  const float* whh1 = (const float*)d_in[6];
  const float* bih1 = (const float*)d_in[7];
  const float* bhh1 = (const float*)d_in[8];
  const float* fcw  = (const float*)d_in[9];
  const float* fcb  = (const float*)d_in[10];
  float* out = (float*)d_out;

  hipLaunchKernelGGL(gru2_f16dot, dim3(Bsz / 4), dim3(128), 0, stream,
                     x, wih0, whh0, bih0, bhh0, wih1, whh1, bih1, bhh1, fcw, fcb, out);
}